// Round 1
// baseline (612.827 us; speedup 1.0000x reference)
//
#include <hip/hip_runtime.h>
#include <math.h>

#define NND 50000
#define NE  600000
#define HD  128
#define NC  10

// ---------------- init: deg=1 (self loop), cnt=0, loss=0 ----------------
__global__ void k_init(float* degf, int* cnt, float* lossb) {
  int i = blockIdx.x * 256 + threadIdx.x;
  if (i < NND) { degf[i] = 1.0f; cnt[i] = 0; }
  if (blockIdx.x == 0 && threadIdx.x == 0) lossb[0] = 0.0f;
}

// ---------------- histogram: deg over row, in-degree count over col ----------------
__global__ void k_count(const int* __restrict__ row, const int* __restrict__ col,
                        float* degf, int* cnt) {
  int e = blockIdx.x * 256 + threadIdx.x;
  if (e < NE) {
    atomicAdd(&cnt[col[e]], 1);
    unsafeAtomicAdd(&degf[row[e]], 1.0f);
  }
}

// ---------------- single-block exclusive scan of cnt -> offs, pos ----------------
__global__ __launch_bounds__(1024) void k_scan(const int* __restrict__ cnt,
                                               int* __restrict__ offs,
                                               int* __restrict__ pos) {
  __shared__ int wsum[16];
  __shared__ int ctot;
  int tid = threadIdx.x;
  int lane = tid & 63, wid = tid >> 6;
  int carry = 0;
  for (int base = 0; base < NND; base += 4096) {
    int i0 = base + tid * 4;
    int v0 = (i0     < NND) ? cnt[i0]     : 0;
    int v1 = (i0 + 1 < NND) ? cnt[i0 + 1] : 0;
    int v2 = (i0 + 2 < NND) ? cnt[i0 + 2] : 0;
    int v3 = (i0 + 3 < NND) ? cnt[i0 + 3] : 0;
    int tsum = v0 + v1 + v2 + v3;
    int x = tsum;
    #pragma unroll
    for (int off = 1; off < 64; off <<= 1) {
      int y = __shfl_up(x, off, 64);
      if (lane >= off) x += y;
    }
    if (lane == 63) wsum[wid] = x;
    __syncthreads();
    if (tid == 0) {
      int s = 0;
      for (int w = 0; w < 16; w++) { int t = wsum[w]; wsum[w] = s; s += t; }
      ctot = s;
    }
    __syncthreads();
    int texcl = carry + wsum[wid] + (x - tsum);
    if (i0     < NND) { offs[i0]     = texcl;              pos[i0]     = texcl; }
    if (i0 + 1 < NND) { offs[i0 + 1] = texcl + v0;         pos[i0 + 1] = texcl + v0; }
    if (i0 + 2 < NND) { offs[i0 + 2] = texcl + v0 + v1;    pos[i0 + 2] = texcl + v0 + v1; }
    if (i0 + 3 < NND) { offs[i0 + 3] = texcl + v0 + v1 + v2; pos[i0 + 3] = texcl + v0 + v1 + v2; }
    carry += ctot;
    __syncthreads();
  }
  if (tid == 0) offs[NND] = carry;
}

// ---------------- dinv = deg^-0.5 (in place) ----------------
__global__ void k_dinv(float* degf) {
  int i = blockIdx.x * 256 + threadIdx.x;
  if (i < NND) degf[i] = rsqrtf(degf[i]);
}

// ---------------- CSR fill: srcs sorted by destination ----------------
__global__ void k_fill(const int* __restrict__ row, const int* __restrict__ col,
                       int* pos, int* __restrict__ srcs) {
  int e = blockIdx.x * 256 + threadIdx.x;
  if (e < NE) {
    int p = atomicAdd(&pos[col[e]], 1);
    srcs[p] = row[e];
  }
}

// ---------------- W transpose: Wt[k][j] = W[j][k] ----------------
__global__ void k_transpose(const float* __restrict__ W, float* __restrict__ Wt) {
  int i = blockIdx.x * 256 + threadIdx.x;  // 16384
  int j = i >> 7, k = i & 127;
  Wt[k * HD + j] = W[j * HD + k];
}

// ---------------- Y[n][j] = b[j] + sum_k X[n][k] * Wt[k][j] ----------------
__global__ __launch_bounds__(256) void k_gemm(const float* __restrict__ X,
                                              const float* __restrict__ Wt,
                                              const float* __restrict__ b,
                                              float* __restrict__ Y) {
  __shared__ float Xs[32][HD];  // [node][k], 16 KB
  int tid = threadIdx.x;
  int nbase = blockIdx.x * 32;
  for (int idx = tid; idx < 32 * 32; idx += 256) {
    int n = idx >> 5;
    int k4 = (idx & 31) * 4;
    int gn = nbase + n;
    float4 v = make_float4(0.f, 0.f, 0.f, 0.f);
    if (gn < NND) v = *(const float4*)&X[gn * HD + k4];
    *(float4*)&Xs[n][k4] = v;
  }
  __syncthreads();
  int jq = (tid & 31) * 4;   // j quad: covers 128 outputs
  int nr = tid >> 5;         // node offset 0..7; nodes nr + 8p
  float4 acc[4];
  #pragma unroll
  for (int p = 0; p < 4; p++) acc[p] = make_float4(0.f, 0.f, 0.f, 0.f);
  const float4* Wt4 = (const float4*)Wt;
  int jqi = jq >> 2;
  for (int k4 = 0; k4 < HD; k4 += 4) {
    float4 w0 = Wt4[(k4 + 0) * 32 + jqi];
    float4 w1 = Wt4[(k4 + 1) * 32 + jqi];
    float4 w2 = Wt4[(k4 + 2) * 32 + jqi];
    float4 w3 = Wt4[(k4 + 3) * 32 + jqi];
    #pragma unroll
    for (int p = 0; p < 4; p++) {
      float4 xv = *(const float4*)&Xs[nr + 8 * p][k4];
      acc[p].x += w0.x * xv.x + w1.x * xv.y + w2.x * xv.z + w3.x * xv.w;
      acc[p].y += w0.y * xv.x + w1.y * xv.y + w2.y * xv.z + w3.y * xv.w;
      acc[p].z += w0.z * xv.x + w1.z * xv.y + w2.z * xv.z + w3.z * xv.w;
      acc[p].w += w0.w * xv.x + w1.w * xv.y + w2.w * xv.z + w3.w * xv.w;
    }
  }
  float4 b4 = *(const float4*)&b[jq];
  #pragma unroll
  for (int p = 0; p < 4; p++) {
    int gn = nbase + nr + 8 * p;
    if (gn < NND) {
      float4 r;
      r.x = acc[p].x + b4.x; r.y = acc[p].y + b4.y;
      r.z = acc[p].z + b4.z; r.w = acc[p].w + b4.w;
      *(float4*)&Y[gn * HD + jq] = r;
    }
  }
}

// ---------------- O[i] = dinv[i]^2*H[i] + sum_{e:col=i} dinv[src]*dinv[i]*H[src] ----------------
__global__ __launch_bounds__(256) void k_aggr(const float* __restrict__ H,
                                              const int* __restrict__ offs,
                                              const int* __restrict__ srcs,
                                              const float* __restrict__ dinv,
                                              float* __restrict__ O) {
  int g = threadIdx.x >> 5, lane = threadIdx.x & 31;
  int node = blockIdx.x * 8 + g;
  if (node >= NND) return;
  float di = dinv[node];
  float4 hv = *(const float4*)&H[node * HD + lane * 4];
  float sw = di * di;
  float4 acc;
  acc.x = hv.x * sw; acc.y = hv.y * sw; acc.z = hv.z * sw; acc.w = hv.w * sw;
  int s0 = offs[node], s1 = offs[node + 1];
  for (int t = s0; t < s1; t++) {
    int s = srcs[t];
    float w = dinv[s] * di;
    float4 hs = *(const float4*)&H[s * HD + lane * 4];
    acc.x += w * hs.x; acc.y += w * hs.y; acc.z += w * hs.z; acc.w += w * hs.w;
  }
  *(float4*)&O[node * HD + lane * 4] = acc;
}

// ---------------- per-edge classifier + log_softmax + NLL ----------------
__global__ __launch_bounds__(256) void k_edge(const float* __restrict__ H,
                                              const int* __restrict__ row,
                                              const int* __restrict__ col,
                                              const int* __restrict__ label,
                                              const float* __restrict__ Wfc,
                                              const float* __restrict__ bfc,
                                              float* __restrict__ logits,
                                              float* __restrict__ lossb) {
  __shared__ float Wf[NC * 256];  // 10 KB
  __shared__ float Bs[16];
  __shared__ float Ls[8];
  int tid = threadIdx.x;
  for (int i = tid; i < NC * 256; i += 256) Wf[i] = Wfc[i];
  if (tid < NC) Bs[tid] = bfc[tid];
  __syncthreads();
  int g = tid >> 5, lane = tid & 31;
  float lsum = 0.0f;
  for (int rep = 0; rep < 8; rep++) {
    int e = blockIdx.x * 64 + rep * 8 + g;  // 9375*64 = 600000 exactly
    int r = row[e], c = col[e];
    float4 hr = *(const float4*)&H[r * HD + lane * 4];
    float4 hc = *(const float4*)&H[c * HD + lane * 4];
    float p[NC];
    #pragma unroll
    for (int cc = 0; cc < NC; cc++) {
      float4 wr = *(const float4*)&Wf[cc * 256 + lane * 4];
      float4 wc = *(const float4*)&Wf[cc * 256 + 128 + lane * 4];
      p[cc] = hr.x * wr.x + hr.y * wr.y + hr.z * wr.z + hr.w * wr.w
            + hc.x * wc.x + hc.y * wc.y + hc.z * wc.z + hc.w * wc.w;
    }
    #pragma unroll
    for (int off = 16; off > 0; off >>= 1) {
      #pragma unroll
      for (int cc = 0; cc < NC; cc++) p[cc] += __shfl_xor(p[cc], off, 32);
    }
    #pragma unroll
    for (int cc = 0; cc < NC; cc++) p[cc] += Bs[cc];
    if (lane < NC) logits[(long long)e * NC + lane] = p[lane];
    if (lane == 0) {
      float m = p[0];
      #pragma unroll
      for (int cc = 1; cc < NC; cc++) m = fmaxf(m, p[cc]);
      float se = 0.f;
      #pragma unroll
      for (int cc = 0; cc < NC; cc++) se += __expf(p[cc] - m);
      int lb = label[e];
      float plb = p[0];
      #pragma unroll
      for (int cc = 1; cc < NC; cc++) plb = (cc == lb) ? p[cc] : plb;
      lsum += plb - m - __logf(se);
    }
  }
  if (lane == 0) Ls[g] = lsum;
  __syncthreads();
  if (tid == 0) {
    float s = 0.f;
    for (int i = 0; i < 8; i++) s += Ls[i];
    unsafeAtomicAdd(lossb, s);
  }
}

__global__ void k_loss(const float* lossb, float* out) {
  out[0] = -lossb[0] / (float)NE;
}

extern "C" void kernel_launch(void* const* d_in, const int* in_sizes, int n_in,
                              void* d_out, int out_size, void* d_ws, size_t ws_size,
                              hipStream_t stream) {
  const float* features = (const float*)d_in[0];
  const float* W1  = (const float*)d_in[1];
  const float* b1  = (const float*)d_in[2];
  const float* W2  = (const float*)d_in[3];
  const float* b2  = (const float*)d_in[4];
  const float* Wfc = (const float*)d_in[5];
  const float* bfc = (const float*)d_in[6];
  const int* row   = (const int*)d_in[7];
  const int* col   = (const int*)d_in[8];
  const int* label = (const int*)d_in[9];
  float* out = (float*)d_out;

  float* ws = (float*)d_ws;
  size_t o = 0;
  float* degf = ws + o;        o += 50048;   // deg -> dinv in place
  int*   cnt  = (int*)(ws + o); o += 50048;
  int*   offs = (int*)(ws + o); o += 50064;  // N+1
  int*   pos  = (int*)(ws + o); o += 50048;
  int*   srcs = (int*)(ws + o); o += 600064;
  float* Wt1  = ws + o;        o += 16384;
  float* Wt2  = ws + o;        o += 16384;
  float* lossb = ws + o;       o += 16;
  float* bufA = ws + o;        o += 6400000;
  float* bufB = ws + o;        o += 6400000;  // total ~54.5 MB

  k_init<<<196, 256, 0, stream>>>(degf, cnt, lossb);
  k_count<<<2344, 256, 0, stream>>>(row, col, degf, cnt);
  k_scan<<<1, 1024, 0, stream>>>(cnt, offs, pos);
  k_dinv<<<196, 256, 0, stream>>>(degf);
  k_fill<<<2344, 256, 0, stream>>>(row, col, pos, srcs);
  k_transpose<<<64, 256, 0, stream>>>(W1, Wt1);
  k_transpose<<<64, 256, 0, stream>>>(W2, Wt2);

  // conv1
  k_gemm<<<1563, 256, 0, stream>>>(features, Wt1, b1, bufA);
  k_aggr<<<6250, 256, 0, stream>>>(bufA, offs, srcs, degf, bufB);
  // conv2
  k_gemm<<<1563, 256, 0, stream>>>(bufB, Wt2, b2, bufA);
  k_aggr<<<6250, 256, 0, stream>>>(bufA, offs, srcs, degf, bufB);
  // edge classifier + loss
  k_edge<<<9375, 256, 0, stream>>>(bufB, row, col, label, Wfc, bfc, out + 1, lossb);
  k_loss<<<1, 1, 0, stream>>>(lossb, out);
}

// Round 2
// 567.620 us; speedup vs baseline: 1.0796x; 1.0796x over previous
//
#include <hip/hip_runtime.h>
#include <hip/hip_bf16.h>
#include <math.h>

#define NND 50000
#define NE  600000
#define HD  128
#define NC  10

typedef unsigned short ushort_t;

__device__ __forceinline__ float bf2f(unsigned short u) {
  return __uint_as_float(((unsigned int)u) << 16);
}
__device__ __forceinline__ unsigned short f2bf(float f) {
  __hip_bfloat16 h = __float2bfloat16(f);  // RNE
  return *(unsigned short*)&h;
}
__device__ __forceinline__ float4 bf4_to_f4(ushort4 u) {
  return make_float4(bf2f(u.x), bf2f(u.y), bf2f(u.z), bf2f(u.w));
}

// ---------------- init: deg=1 (self loop), cnt=0, loss=0 ----------------
__global__ void k_init(float* degf, int* cnt, float* lossb) {
  int i = blockIdx.x * 256 + threadIdx.x;
  if (i < NND) { degf[i] = 1.0f; cnt[i] = 0; }
  if (blockIdx.x == 0 && threadIdx.x == 0) lossb[0] = 0.0f;
}

// ---------------- histogram: deg over row, in-degree count over col ----------------
__global__ void k_count(const int* __restrict__ row, const int* __restrict__ col,
                        float* degf, int* cnt) {
  int e = blockIdx.x * 256 + threadIdx.x;
  if (e < NE) {
    atomicAdd(&cnt[col[e]], 1);
    unsafeAtomicAdd(&degf[row[e]], 1.0f);
  }
}

// ---------------- single-block exclusive scan of cnt -> offs, pos ----------------
__global__ __launch_bounds__(1024) void k_scan(const int* __restrict__ cnt,
                                               int* __restrict__ offs,
                                               int* __restrict__ pos) {
  __shared__ int wsum[16];
  __shared__ int ctot;
  int tid = threadIdx.x;
  int lane = tid & 63, wid = tid >> 6;
  int carry = 0;
  for (int base = 0; base < NND; base += 4096) {
    int i0 = base + tid * 4;
    int v0 = (i0     < NND) ? cnt[i0]     : 0;
    int v1 = (i0 + 1 < NND) ? cnt[i0 + 1] : 0;
    int v2 = (i0 + 2 < NND) ? cnt[i0 + 2] : 0;
    int v3 = (i0 + 3 < NND) ? cnt[i0 + 3] : 0;
    int tsum = v0 + v1 + v2 + v3;
    int x = tsum;
    #pragma unroll
    for (int off = 1; off < 64; off <<= 1) {
      int y = __shfl_up(x, off, 64);
      if (lane >= off) x += y;
    }
    if (lane == 63) wsum[wid] = x;
    __syncthreads();
    if (tid == 0) {
      int s = 0;
      for (int w = 0; w < 16; w++) { int t = wsum[w]; wsum[w] = s; s += t; }
      ctot = s;
    }
    __syncthreads();
    int texcl = carry + wsum[wid] + (x - tsum);
    if (i0     < NND) { offs[i0]     = texcl;                pos[i0]     = texcl; }
    if (i0 + 1 < NND) { offs[i0 + 1] = texcl + v0;           pos[i0 + 1] = texcl + v0; }
    if (i0 + 2 < NND) { offs[i0 + 2] = texcl + v0 + v1;      pos[i0 + 2] = texcl + v0 + v1; }
    if (i0 + 3 < NND) { offs[i0 + 3] = texcl + v0 + v1 + v2; pos[i0 + 3] = texcl + v0 + v1 + v2; }
    carry += ctot;
    __syncthreads();
  }
  if (tid == 0) offs[NND] = carry;
}

// ---------------- dinv = deg^-0.5 (in place) ----------------
__global__ void k_dinv(float* degf) {
  int i = blockIdx.x * 256 + threadIdx.x;
  if (i < NND) degf[i] = rsqrtf(degf[i]);
}

// ---------------- CSR fill: srcs sorted by destination ----------------
__global__ void k_fill(const int* __restrict__ row, const int* __restrict__ col,
                       int* pos, int* __restrict__ srcs) {
  int e = blockIdx.x * 256 + threadIdx.x;
  if (e < NE) {
    int p = atomicAdd(&pos[col[e]], 1);
    srcs[p] = row[e];
  }
}

// ---------------- W transpose: Wt[k][j] = W[j][k] ----------------
__global__ void k_transpose(const float* __restrict__ W, float* __restrict__ Wt) {
  int i = blockIdx.x * 256 + threadIdx.x;  // 16384
  int j = i >> 7, k = i & 127;
  Wt[k * HD + j] = W[j * HD + k];
}

// ---------------- GEMM: Y[n][j] = b[j] + sum_k X[n][k] * Wt[k][j]; Y is bf16 ----------------
template <bool BF16IN>
__global__ __launch_bounds__(256) void k_gemm(const void* __restrict__ Xv,
                                              const float* __restrict__ Wt,
                                              const float* __restrict__ b,
                                              ushort_t* __restrict__ Y) {
  __shared__ float Xs[32][HD];  // 16 KB
  int tid = threadIdx.x;
  int nbase = blockIdx.x * 32;
  for (int idx = tid; idx < 32 * 32; idx += 256) {
    int n = idx >> 5;
    int k4 = (idx & 31) * 4;
    int gn = nbase + n;
    float4 v = make_float4(0.f, 0.f, 0.f, 0.f);
    if (gn < NND) {
      if (BF16IN) {
        ushort4 u = *(const ushort4*)&((const ushort_t*)Xv)[gn * HD + k4];
        v = bf4_to_f4(u);
      } else {
        v = *(const float4*)&((const float*)Xv)[gn * HD + k4];
      }
    }
    *(float4*)&Xs[n][k4] = v;
  }
  __syncthreads();
  int jq = (tid & 31) * 4;
  int nr = tid >> 5;
  float4 acc[4];
  #pragma unroll
  for (int p = 0; p < 4; p++) acc[p] = make_float4(0.f, 0.f, 0.f, 0.f);
  const float4* Wt4 = (const float4*)Wt;
  int jqi = jq >> 2;
  for (int k4 = 0; k4 < HD; k4 += 4) {
    float4 w0 = Wt4[(k4 + 0) * 32 + jqi];
    float4 w1 = Wt4[(k4 + 1) * 32 + jqi];
    float4 w2 = Wt4[(k4 + 2) * 32 + jqi];
    float4 w3 = Wt4[(k4 + 3) * 32 + jqi];
    #pragma unroll
    for (int p = 0; p < 4; p++) {
      float4 xv = *(const float4*)&Xs[nr + 8 * p][k4];
      acc[p].x += w0.x * xv.x + w1.x * xv.y + w2.x * xv.z + w3.x * xv.w;
      acc[p].y += w0.y * xv.x + w1.y * xv.y + w2.y * xv.z + w3.y * xv.w;
      acc[p].z += w0.z * xv.x + w1.z * xv.y + w2.z * xv.z + w3.z * xv.w;
      acc[p].w += w0.w * xv.x + w1.w * xv.y + w2.w * xv.z + w3.w * xv.w;
    }
  }
  float4 b4 = *(const float4*)&b[jq];
  #pragma unroll
  for (int p = 0; p < 4; p++) {
    int gn = nbase + nr + 8 * p;
    if (gn < NND) {
      ushort4 r;
      r.x = f2bf(acc[p].x + b4.x); r.y = f2bf(acc[p].y + b4.y);
      r.z = f2bf(acc[p].z + b4.z); r.w = f2bf(acc[p].w + b4.w);
      *(ushort4*)&Y[gn * HD + jq] = r;
    }
  }
}

// ---------------- aggregation over bf16 rows, fp32 accumulate, bf16 out ----------------
__global__ __launch_bounds__(256) void k_aggr(const ushort_t* __restrict__ H,
                                              const int* __restrict__ offs,
                                              const int* __restrict__ srcs,
                                              const float* __restrict__ dinv,
                                              ushort_t* __restrict__ O) {
  int g = threadIdx.x >> 5, lane = threadIdx.x & 31;
  int node = blockIdx.x * 8 + g;
  if (node >= NND) return;
  float di = dinv[node];
  float4 hv = bf4_to_f4(*(const ushort4*)&H[node * HD + lane * 4]);
  float sw = di * di;
  float4 acc;
  acc.x = hv.x * sw; acc.y = hv.y * sw; acc.z = hv.z * sw; acc.w = hv.w * sw;
  int s0 = offs[node], s1 = offs[node + 1];
  for (int base = s0; base < s1; base += 32) {
    int m = s1 - base; if (m > 32) m = 32;
    int sl = 0; float wl = 0.f;
    if (lane < m) { sl = srcs[base + lane]; wl = dinv[sl]; }
    for (int t = 0; t < m; t++) {
      int s = __shfl(sl, t, 32);
      float w = __shfl(wl, t, 32) * di;
      float4 hs = bf4_to_f4(*(const ushort4*)&H[s * HD + lane * 4]);
      acc.x += w * hs.x; acc.y += w * hs.y; acc.z += w * hs.z; acc.w += w * hs.w;
    }
  }
  ushort4 r;
  r.x = f2bf(acc.x); r.y = f2bf(acc.y); r.z = f2bf(acc.z); r.w = f2bf(acc.w);
  *(ushort4*)&O[node * HD + lane * 4] = r;
}

// ---------------- per-edge classifier + log_softmax + NLL ----------------
__global__ __launch_bounds__(256) void k_edge(const ushort_t* __restrict__ H,
                                              const int* __restrict__ row,
                                              const int* __restrict__ col,
                                              const int* __restrict__ label,
                                              const float* __restrict__ Wfc,
                                              const float* __restrict__ bfc,
                                              float* __restrict__ logits,
                                              float* __restrict__ lossb) {
  __shared__ float Wf[NC * 256];  // 10 KB
  __shared__ float Bs[16];
  __shared__ float Ls[8];
  int tid = threadIdx.x;
  for (int i = tid; i < NC * 256; i += 256) Wf[i] = Wfc[i];
  if (tid < NC) Bs[tid] = bfc[tid];
  __syncthreads();
  int g = tid >> 5, lane = tid & 31;
  float lsum = 0.0f;
  for (int rep = 0; rep < 8; rep++) {
    int e = blockIdx.x * 64 + rep * 8 + g;  // 9375*64 = 600000 exactly
    int r = row[e], c = col[e];
    float4 hr = bf4_to_f4(*(const ushort4*)&H[r * HD + lane * 4]);
    float4 hc = bf4_to_f4(*(const ushort4*)&H[c * HD + lane * 4]);
    float p[NC];
    #pragma unroll
    for (int cc = 0; cc < NC; cc++) {
      float4 wr = *(const float4*)&Wf[cc * 256 + lane * 4];
      float4 wc = *(const float4*)&Wf[cc * 256 + 128 + lane * 4];
      p[cc] = hr.x * wr.x + hr.y * wr.y + hr.z * wr.z + hr.w * wr.w
            + hc.x * wc.x + hc.y * wc.y + hc.z * wc.z + hc.w * wc.w;
    }
    #pragma unroll
    for (int off = 16; off > 0; off >>= 1) {
      #pragma unroll
      for (int cc = 0; cc < NC; cc++) p[cc] += __shfl_xor(p[cc], off, 32);
    }
    #pragma unroll
    for (int cc = 0; cc < NC; cc++) p[cc] += Bs[cc];
    if (lane < NC) logits[(long long)e * NC + lane] = p[lane];
    if (lane == 0) {
      float m = p[0];
      #pragma unroll
      for (int cc = 1; cc < NC; cc++) m = fmaxf(m, p[cc]);
      float se = 0.f;
      #pragma unroll
      for (int cc = 0; cc < NC; cc++) se += __expf(p[cc] - m);
      int lb = label[e];
      float plb = p[0];
      #pragma unroll
      for (int cc = 1; cc < NC; cc++) plb = (cc == lb) ? p[cc] : plb;
      lsum += plb - m - __logf(se);
    }
  }
  if (lane == 0) Ls[g] = lsum;
  __syncthreads();
  if (tid == 0) {
    float s = 0.f;
    for (int i = 0; i < 8; i++) s += Ls[i];
    unsafeAtomicAdd(lossb, s);
  }
}

__global__ void k_loss(const float* lossb, float* out) {
  out[0] = -lossb[0] / (float)NE;
}

extern "C" void kernel_launch(void* const* d_in, const int* in_sizes, int n_in,
                              void* d_out, int out_size, void* d_ws, size_t ws_size,
                              hipStream_t stream) {
  const float* features = (const float*)d_in[0];
  const float* W1  = (const float*)d_in[1];
  const float* b1  = (const float*)d_in[2];
  const float* W2  = (const float*)d_in[3];
  const float* b2  = (const float*)d_in[4];
  const float* Wfc = (const float*)d_in[5];
  const float* bfc = (const float*)d_in[6];
  const int* row   = (const int*)d_in[7];
  const int* col   = (const int*)d_in[8];
  const int* label = (const int*)d_in[9];
  float* out = (float*)d_out;

  float* ws = (float*)d_ws;
  size_t o = 0;
  float* degf = ws + o;         o += 50048;
  int*   cnt  = (int*)(ws + o); o += 50048;
  int*   offs = (int*)(ws + o); o += 50064;  // N+1
  int*   pos  = (int*)(ws + o); o += 50048;
  int*   srcs = (int*)(ws + o); o += 600064;
  float* Wt1  = ws + o;         o += 16384;
  float* Wt2  = ws + o;         o += 16384;
  float* lossb = ws + o;        o += 16;
  ushort_t* bufA = (ushort_t*)(ws + o); o += 3200000;  // 50000*128 bf16
  ushort_t* bufB = (ushort_t*)(ws + o); o += 3200000;  // total ~29 MB

  k_init<<<196, 256, 0, stream>>>(degf, cnt, lossb);
  k_count<<<2344, 256, 0, stream>>>(row, col, degf, cnt);
  k_scan<<<1, 1024, 0, stream>>>(cnt, offs, pos);
  k_dinv<<<196, 256, 0, stream>>>(degf);
  k_fill<<<2344, 256, 0, stream>>>(row, col, pos, srcs);
  k_transpose<<<64, 256, 0, stream>>>(W1, Wt1);
  k_transpose<<<64, 256, 0, stream>>>(W2, Wt2);

  // conv1: gemm (fp32 in, bf16 out) then aggregate (bf16 -> bf16)
  k_gemm<false><<<1563, 256, 0, stream>>>((const void*)features, Wt1, b1, bufA);
  k_aggr<<<6250, 256, 0, stream>>>(bufA, offs, srcs, degf, bufB);
  // conv2
  k_gemm<true><<<1563, 256, 0, stream>>>((const void*)bufB, Wt2, b2, bufA);
  k_aggr<<<6250, 256, 0, stream>>>(bufA, offs, srcs, degf, bufB);
  // edge classifier + loss
  k_edge<<<9375, 256, 0, stream>>>(bufB, row, col, label, Wfc, bfc, out + 1, lossb);
  k_loss<<<1, 1, 0, stream>>>(lossb, out);
}

// Round 3
// 434.083 us; speedup vs baseline: 1.4118x; 1.3076x over previous
//
#include <hip/hip_runtime.h>
#include <hip/hip_bf16.h>
#include <math.h>

#define NND 50000
#define NE  600000
#define HD  128
#define NC  10

typedef unsigned short ushort_t;
typedef __attribute__((ext_vector_type(8))) short short8;
typedef __attribute__((ext_vector_type(4))) float f32x4;

__device__ __forceinline__ float bf2f(unsigned short u) {
  return __uint_as_float(((unsigned int)u) << 16);
}
__device__ __forceinline__ unsigned short f2bf(float f) {
  __hip_bfloat16 h = __float2bfloat16(f);  // RNE
  return *(unsigned short*)&h;
}
__device__ __forceinline__ float4 bf4_to_f4(ushort4 u) {
  return make_float4(bf2f(u.x), bf2f(u.y), bf2f(u.z), bf2f(u.w));
}

// ---------------- init: deg=1 (self loop), cnt=0, loss=0 ----------------
__global__ void k_init(float* degf, int* cnt, float* lossb) {
  int i = blockIdx.x * 256 + threadIdx.x;
  if (i < NND) { degf[i] = 1.0f; cnt[i] = 0; }
  if (blockIdx.x == 0 && threadIdx.x == 0) lossb[0] = 0.0f;
}

// ---------------- histogram ----------------
__global__ void k_count(const int* __restrict__ row, const int* __restrict__ col,
                        float* degf, int* cnt) {
  int e = blockIdx.x * 256 + threadIdx.x;
  if (e < NE) {
    atomicAdd(&cnt[col[e]], 1);
    unsafeAtomicAdd(&degf[row[e]], 1.0f);
  }
}

// ---------------- single-block exclusive scan ----------------
__global__ __launch_bounds__(1024) void k_scan(const int* __restrict__ cnt,
                                               int* __restrict__ offs,
                                               int* __restrict__ pos) {
  __shared__ int wsum[16];
  __shared__ int ctot;
  int tid = threadIdx.x;
  int lane = tid & 63, wid = tid >> 6;
  int carry = 0;
  for (int base = 0; base < NND; base += 4096) {
    int i0 = base + tid * 4;
    int v0 = (i0     < NND) ? cnt[i0]     : 0;
    int v1 = (i0 + 1 < NND) ? cnt[i0 + 1] : 0;
    int v2 = (i0 + 2 < NND) ? cnt[i0 + 2] : 0;
    int v3 = (i0 + 3 < NND) ? cnt[i0 + 3] : 0;
    int tsum = v0 + v1 + v2 + v3;
    int x = tsum;
    #pragma unroll
    for (int off = 1; off < 64; off <<= 1) {
      int y = __shfl_up(x, off, 64);
      if (lane >= off) x += y;
    }
    if (lane == 63) wsum[wid] = x;
    __syncthreads();
    if (tid == 0) {
      int s = 0;
      for (int w = 0; w < 16; w++) { int t = wsum[w]; wsum[w] = s; s += t; }
      ctot = s;
    }
    __syncthreads();
    int texcl = carry + wsum[wid] + (x - tsum);
    if (i0     < NND) { offs[i0]     = texcl;                pos[i0]     = texcl; }
    if (i0 + 1 < NND) { offs[i0 + 1] = texcl + v0;           pos[i0 + 1] = texcl + v0; }
    if (i0 + 2 < NND) { offs[i0 + 2] = texcl + v0 + v1;      pos[i0 + 2] = texcl + v0 + v1; }
    if (i0 + 3 < NND) { offs[i0 + 3] = texcl + v0 + v1 + v2; pos[i0 + 3] = texcl + v0 + v1 + v2; }
    carry += ctot;
    __syncthreads();
  }
  if (tid == 0) offs[NND] = carry;
}

__global__ void k_dinv(float* degf) {
  int i = blockIdx.x * 256 + threadIdx.x;
  if (i < NND) degf[i] = rsqrtf(degf[i]);
}

__global__ void k_fill(const int* __restrict__ row, const int* __restrict__ col,
                       int* pos, int* __restrict__ srcs) {
  int e = blockIdx.x * 256 + threadIdx.x;
  if (e < NE) {
    int p = atomicAdd(&pos[col[e]], 1);
    srcs[p] = row[e];
  }
}

__global__ void k_transpose(const float* __restrict__ W, float* __restrict__ Wt) {
  int i = blockIdx.x * 256 + threadIdx.x;  // 16384
  int j = i >> 7, k = i & 127;
  Wt[k * HD + j] = W[j * HD + k];
}

// ---------------- pack Wfc into MFMA B-fragment order, bf16, 16-padded ----------------
// B[n=lane&15][k=quad*8+j], k in [0,256): Bp[(t*64+lane)*8 + j] = Wfc[n][t*32+quad*8+j]
__global__ void k_prep(const float* __restrict__ Wfc, ushort_t* __restrict__ Bp) {
  int tid = threadIdx.x;  // 256
  for (int idx = tid; idx < 8 * 64; idx += 256) {
    int t = idx >> 6, lane = idx & 63;
    int n = lane & 15, q = lane >> 4;
    #pragma unroll
    for (int j = 0; j < 8; j++) {
      int k = t * 32 + q * 8 + j;
      float v = (n < NC) ? Wfc[n * 256 + k] : 0.f;
      Bp[idx * 8 + j] = f2bf(v);
    }
  }
}

// ---------------- GEMM: Y[n][j] = b[j] + sum_k X[n][k]*Wt[k][j]; Y bf16 ----------------
template <bool BF16IN>
__global__ __launch_bounds__(256) void k_gemm(const void* __restrict__ Xv,
                                              const float* __restrict__ Wt,
                                              const float* __restrict__ b,
                                              ushort_t* __restrict__ Y) {
  __shared__ float Xs[32][HD];
  int tid = threadIdx.x;
  int nbase = blockIdx.x * 32;
  for (int idx = tid; idx < 32 * 32; idx += 256) {
    int n = idx >> 5;
    int k4 = (idx & 31) * 4;
    int gn = nbase + n;
    float4 v = make_float4(0.f, 0.f, 0.f, 0.f);
    if (gn < NND) {
      if (BF16IN) {
        ushort4 u = *(const ushort4*)&((const ushort_t*)Xv)[gn * HD + k4];
        v = bf4_to_f4(u);
      } else {
        v = *(const float4*)&((const float*)Xv)[gn * HD + k4];
      }
    }
    *(float4*)&Xs[n][k4] = v;
  }
  __syncthreads();
  int jq = (tid & 31) * 4;
  int nr = tid >> 5;
  float4 acc[4];
  #pragma unroll
  for (int p = 0; p < 4; p++) acc[p] = make_float4(0.f, 0.f, 0.f, 0.f);
  const float4* Wt4 = (const float4*)Wt;
  int jqi = jq >> 2;
  for (int k4 = 0; k4 < HD; k4 += 4) {
    float4 w0 = Wt4[(k4 + 0) * 32 + jqi];
    float4 w1 = Wt4[(k4 + 1) * 32 + jqi];
    float4 w2 = Wt4[(k4 + 2) * 32 + jqi];
    float4 w3 = Wt4[(k4 + 3) * 32 + jqi];
    #pragma unroll
    for (int p = 0; p < 4; p++) {
      float4 xv = *(const float4*)&Xs[nr + 8 * p][k4];
      acc[p].x += w0.x * xv.x + w1.x * xv.y + w2.x * xv.z + w3.x * xv.w;
      acc[p].y += w0.y * xv.x + w1.y * xv.y + w2.y * xv.z + w3.y * xv.w;
      acc[p].z += w0.z * xv.x + w1.z * xv.y + w2.z * xv.z + w3.z * xv.w;
      acc[p].w += w0.w * xv.x + w1.w * xv.y + w2.w * xv.z + w3.w * xv.w;
    }
  }
  float4 b4 = *(const float4*)&b[jq];
  #pragma unroll
  for (int p = 0; p < 4; p++) {
    int gn = nbase + nr + 8 * p;
    if (gn < NND) {
      ushort4 r;
      r.x = f2bf(acc[p].x + b4.x); r.y = f2bf(acc[p].y + b4.y);
      r.z = f2bf(acc[p].z + b4.z); r.w = f2bf(acc[p].w + b4.w);
      *(ushort4*)&Y[gn * HD + jq] = r;
    }
  }
}

// ---------------- aggregation: bf16 rows, fp32 accumulate, bf16 out ----------------
__global__ __launch_bounds__(256) void k_aggr(const ushort_t* __restrict__ H,
                                              const int* __restrict__ offs,
                                              const int* __restrict__ srcs,
                                              const float* __restrict__ dinv,
                                              ushort_t* __restrict__ O) {
  int g = threadIdx.x >> 5, lane = threadIdx.x & 31;
  int node = blockIdx.x * 8 + g;
  if (node >= NND) return;
  float di = dinv[node];
  float4 hv = bf4_to_f4(*(const ushort4*)&H[node * HD + lane * 4]);
  float sw = di * di;
  float4 acc;
  acc.x = hv.x * sw; acc.y = hv.y * sw; acc.z = hv.z * sw; acc.w = hv.w * sw;
  int s0 = offs[node], s1 = offs[node + 1];
  for (int base = s0; base < s1; base += 32) {
    int m = s1 - base; if (m > 32) m = 32;
    int sl = 0; float wl = 0.f;
    if (lane < m) { sl = srcs[base + lane]; wl = dinv[sl]; }
    for (int t = 0; t < m; t++) {
      int s = __shfl(sl, t, 32);
      float w = __shfl(wl, t, 32) * di;
      float4 hs = bf4_to_f4(*(const ushort4*)&H[s * HD + lane * 4]);
      acc.x += w * hs.x; acc.y += w * hs.y; acc.z += w * hs.z; acc.w += w * hs.w;
    }
  }
  ushort4 r;
  r.x = f2bf(acc.x); r.y = f2bf(acc.y); r.z = f2bf(acc.z); r.w = f2bf(acc.w);
  *(ushort4*)&O[node * HD + lane * 4] = r;
}

// ---------------- edge classifier via MFMA: 16 edges x 16 classes per wave ----------------
__global__ __launch_bounds__(256) void k_edge(const ushort_t* __restrict__ H,
                                              const int* __restrict__ row,
                                              const int* __restrict__ col,
                                              const ushort_t* __restrict__ Bp,
                                              const float* __restrict__ bfc,
                                              float* __restrict__ logits) {
  int tid = threadIdx.x;
  int w = tid >> 6, lane = tid & 63;
  int ebase = blockIdx.x * 64 + w * 16;  // 9375*64 = 600000 exactly
  int m = lane & 15, g = lane >> 4;

  // B fragments (constant per kernel): 8 x short8 = 32 VGPRs
  short8 bf[8];
  #pragma unroll
  for (int t = 0; t < 8; t++) bf[t] = *(const short8*)&Bp[(t * 64 + lane) * 8];

  int r = row[ebase + m];
  int c = col[ebase + m];
  long br = (long)r * HD, bc = (long)c * HD;
  int ko = g * 8;

  // 8 independent 16B gathers (A fragments: A[m=lane&15][k=quad*8+j])
  short8 a[8];
  #pragma unroll
  for (int t = 0; t < 4; t++) {
    a[t]     = *(const short8*)&H[br + t * 32 + ko];
    a[4 + t] = *(const short8*)&H[bc + t * 32 + ko];
  }

  f32x4 acc = {0.f, 0.f, 0.f, 0.f};
  #pragma unroll
  for (int t = 0; t < 8; t++)
    acc = __builtin_amdgcn_mfma_f32_16x16x32_bf16(a[t], bf[t], acc, 0, 0, 0);

  // C layout: col = lane&15 (class), row = g*4 + reg (edge within tile)
  int n = lane & 15;
  if (n < NC) {
    float bias = bfc[n];
    #pragma unroll
    for (int reg = 0; reg < 4; reg++) {
      int e = ebase + g * 4 + reg;
      logits[(long)e * NC + n] = acc[reg] + bias;
    }
  }
}

// ---------------- loss: streaming log_softmax + NLL over logits ----------------
__global__ __launch_bounds__(256) void k_loss2(const float* __restrict__ logits,
                                               const int* __restrict__ label,
                                               float* __restrict__ lossb) {
  __shared__ float Ls[4];
  int tid = threadIdx.x;
  int e = blockIdx.x * 256 + tid;
  float lp = 0.f;
  if (e < NE) {
    const float* q = logits + (long)e * NC;
    float p[NC];
    #pragma unroll
    for (int i = 0; i < 5; i++) {
      float2 v = *(const float2*)&q[i * 2];
      p[i * 2] = v.x; p[i * 2 + 1] = v.y;
    }
    float mx = p[0];
    #pragma unroll
    for (int cc = 1; cc < NC; cc++) mx = fmaxf(mx, p[cc]);
    float se = 0.f;
    #pragma unroll
    for (int cc = 0; cc < NC; cc++) se += __expf(p[cc] - mx);
    int lb = label[e];
    float plb = p[0];
    #pragma unroll
    for (int cc = 1; cc < NC; cc++) plb = (cc == lb) ? p[cc] : plb;
    lp = plb - mx - __logf(se);
  }
  #pragma unroll
  for (int off = 32; off > 0; off >>= 1) lp += __shfl_xor(lp, off, 64);
  if ((tid & 63) == 0) Ls[tid >> 6] = lp;
  __syncthreads();
  if (tid == 0) {
    float s = Ls[0] + Ls[1] + Ls[2] + Ls[3];
    unsafeAtomicAdd(lossb, s);
  }
}

__global__ void k_loss(const float* lossb, float* out) {
  out[0] = -lossb[0] / (float)NE;
}

extern "C" void kernel_launch(void* const* d_in, const int* in_sizes, int n_in,
                              void* d_out, int out_size, void* d_ws, size_t ws_size,
                              hipStream_t stream) {
  const float* features = (const float*)d_in[0];
  const float* W1  = (const float*)d_in[1];
  const float* b1  = (const float*)d_in[2];
  const float* W2  = (const float*)d_in[3];
  const float* b2  = (const float*)d_in[4];
  const float* Wfc = (const float*)d_in[5];
  const float* bfc = (const float*)d_in[6];
  const int* row   = (const int*)d_in[7];
  const int* col   = (const int*)d_in[8];
  const int* label = (const int*)d_in[9];
  float* out = (float*)d_out;

  float* ws = (float*)d_ws;
  size_t o = 0;
  float* degf = ws + o;         o += 50048;
  int*   cnt  = (int*)(ws + o); o += 50048;
  int*   offs = (int*)(ws + o); o += 50064;  // N+1
  int*   pos  = (int*)(ws + o); o += 50048;
  int*   srcs = (int*)(ws + o); o += 600064;
  float* Wt1  = ws + o;         o += 16384;
  float* Wt2  = ws + o;         o += 16384;
  float* lossb = ws + o;        o += 16;
  ushort_t* Bp = (ushort_t*)(ws + o); o += 2048;  // 4096 bf16
  ushort_t* bufA = (ushort_t*)(ws + o); o += 3200000;
  ushort_t* bufB = (ushort_t*)(ws + o); o += 3200000;

  k_init<<<196, 256, 0, stream>>>(degf, cnt, lossb);
  k_count<<<2344, 256, 0, stream>>>(row, col, degf, cnt);
  k_scan<<<1, 1024, 0, stream>>>(cnt, offs, pos);
  k_dinv<<<196, 256, 0, stream>>>(degf);
  k_fill<<<2344, 256, 0, stream>>>(row, col, pos, srcs);
  k_transpose<<<64, 256, 0, stream>>>(W1, Wt1);
  k_transpose<<<64, 256, 0, stream>>>(W2, Wt2);
  k_prep<<<1, 256, 0, stream>>>(Wfc, Bp);

  // conv1
  k_gemm<false><<<1563, 256, 0, stream>>>((const void*)features, Wt1, b1, bufA);
  k_aggr<<<6250, 256, 0, stream>>>(bufA, offs, srcs, degf, bufB);
  // conv2
  k_gemm<true><<<1563, 256, 0, stream>>>((const void*)bufB, Wt2, b2, bufA);
  k_aggr<<<6250, 256, 0, stream>>>(bufA, offs, srcs, degf, bufB);
  // edge classifier (MFMA) + loss
  k_edge<<<9375, 256, 0, stream>>>(bufB, row, col, Bp, bfc, out + 1);
  k_loss2<<<2344, 256, 0, stream>>>(out + 1, label, lossb);
  k_loss<<<1, 1, 0, stream>>>(lossb, out);
}

// Round 4
// 398.493 us; speedup vs baseline: 1.5379x; 1.0893x over previous
//
#include <hip/hip_runtime.h>
#include <hip/hip_bf16.h>
#include <math.h>

#define NND 50000
#define NE  600000
#define HD  128
#define NC  10

typedef unsigned short ushort_t;
typedef __attribute__((ext_vector_type(8))) short short8;
typedef __attribute__((ext_vector_type(4))) float f32x4;

__device__ __forceinline__ float bf2f(unsigned short u) {
  return __uint_as_float(((unsigned int)u) << 16);
}
__device__ __forceinline__ unsigned short f2bf(float f) {
  __hip_bfloat16 h = __float2bfloat16(f);  // RNE
  return *(unsigned short*)&h;
}
__device__ __forceinline__ float4 bf4_to_f4(ushort4 u) {
  return make_float4(bf2f(u.x), bf2f(u.y), bf2f(u.z), bf2f(u.w));
}

// ---------------- init: deg=1 (self loop), cnt=0, loss=0 ----------------
__global__ void k_init(float* degf, int* cnt, float* lossb) {
  int i = blockIdx.x * 256 + threadIdx.x;
  if (i < NND) { degf[i] = 1.0f; cnt[i] = 0; }
  if (blockIdx.x == 0 && threadIdx.x == 0) lossb[0] = 0.0f;
}

// ---------------- histogram: grid-stride, many independent atomics in flight ----------------
__global__ void k_count(const int* __restrict__ row, const int* __restrict__ col,
                        float* degf, int* cnt) {
  int i0 = blockIdx.x * 256 + threadIdx.x;
  for (int e = i0; e < NE; e += 256 * 256) {
    atomicAdd(&cnt[col[e]], 1);
    unsafeAtomicAdd(&degf[row[e]], 1.0f);
  }
}

// ---------------- single-block exclusive scan (+ dinv fused) ----------------
__global__ __launch_bounds__(1024) void k_scan(const int* __restrict__ cnt,
                                               int* __restrict__ offs,
                                               int* __restrict__ pos,
                                               float* degf) {
  __shared__ int wsum[16];
  __shared__ int ctot;
  int tid = threadIdx.x;
  int lane = tid & 63, wid = tid >> 6;
  int carry = 0;
  for (int base = 0; base < NND; base += 4096) {
    int i0 = base + tid * 4;
    if (i0     < NND) degf[i0]     = rsqrtf(degf[i0]);
    if (i0 + 1 < NND) degf[i0 + 1] = rsqrtf(degf[i0 + 1]);
    if (i0 + 2 < NND) degf[i0 + 2] = rsqrtf(degf[i0 + 2]);
    if (i0 + 3 < NND) degf[i0 + 3] = rsqrtf(degf[i0 + 3]);
    int v0 = (i0     < NND) ? cnt[i0]     : 0;
    int v1 = (i0 + 1 < NND) ? cnt[i0 + 1] : 0;
    int v2 = (i0 + 2 < NND) ? cnt[i0 + 2] : 0;
    int v3 = (i0 + 3 < NND) ? cnt[i0 + 3] : 0;
    int tsum = v0 + v1 + v2 + v3;
    int x = tsum;
    #pragma unroll
    for (int off = 1; off < 64; off <<= 1) {
      int y = __shfl_up(x, off, 64);
      if (lane >= off) x += y;
    }
    if (lane == 63) wsum[wid] = x;
    __syncthreads();
    if (tid == 0) {
      int s = 0;
      for (int w = 0; w < 16; w++) { int t = wsum[w]; wsum[w] = s; s += t; }
      ctot = s;
    }
    __syncthreads();
    int texcl = carry + wsum[wid] + (x - tsum);
    if (i0     < NND) { offs[i0]     = texcl;                pos[i0]     = texcl; }
    if (i0 + 1 < NND) { offs[i0 + 1] = texcl + v0;           pos[i0 + 1] = texcl + v0; }
    if (i0 + 2 < NND) { offs[i0 + 2] = texcl + v0 + v1;      pos[i0 + 2] = texcl + v0 + v1; }
    if (i0 + 3 < NND) { offs[i0 + 3] = texcl + v0 + v1 + v2; pos[i0 + 3] = texcl + v0 + v1 + v2; }
    carry += ctot;
    __syncthreads();
  }
  if (tid == 0) offs[NND] = carry;
}

// ---------------- CSR fill: grid-stride ----------------
__global__ void k_fill(const int* __restrict__ row, const int* __restrict__ col,
                       int* pos, int* __restrict__ srcs) {
  int i0 = blockIdx.x * 256 + threadIdx.x;
  for (int e = i0; e < NE; e += 256 * 256) {
    int p = atomicAdd(&pos[col[e]], 1);
    srcs[p] = row[e];
  }
}

// ---------------- pack all weights into MFMA B-fragment order (bf16) ----------------
// B-frag layout (proven in R3 k_edge): Bfrag[(t*64+lane)*8+j] = W[n=lane&15][k=t*32+(lane>>4)*8+j]
// block 0: Wfc (K=256, 1 n-tile, 16-padded); blocks 1-8: W1 nt=0..7; blocks 9-16: W2.
__global__ void k_prep_all(const float* __restrict__ Wfc, const float* __restrict__ W1,
                           const float* __restrict__ W2, ushort_t* __restrict__ Bp,
                           ushort_t* __restrict__ Bw1, ushort_t* __restrict__ Bw2) {
  int tid = threadIdx.x;
  int bb = blockIdx.x;
  if (bb == 0) {
    for (int idx = tid; idx < 8 * 64; idx += 256) {
      int t = idx >> 6, lane = idx & 63;
      int n = lane & 15, q = (lane >> 4) & 3;
      #pragma unroll
      for (int j = 0; j < 8; j++) {
        int k = t * 32 + q * 8 + j;
        float v = (n < NC) ? Wfc[n * 256 + k] : 0.f;
        Bp[idx * 8 + j] = f2bf(v);
      }
    }
  } else {
    const float* W = (bb <= 8) ? W1 : W2;
    ushort_t* B = (bb <= 8) ? Bw1 : Bw2;
    int nt = (bb - 1) & 7;
    for (int idx = tid; idx < 4 * 64; idx += 256) {
      int t = idx >> 6, lane = idx & 63;
      int n = nt * 16 + (lane & 15), q = (lane >> 4) & 3;
      #pragma unroll
      for (int j = 0; j < 8; j++) {
        int k = t * 32 + q * 8 + j;
        B[(nt * 256 + idx) * 8 + j] = f2bf(W[n * HD + k]);
      }
    }
  }
}

// ---------------- node GEMM via MFMA: Y[r][n] = b[n] + sum_k X[r][k]*W[n][k] ----------------
// 64 rows/block (16/wave); B (128x128 bf16 fragments) staged in 32 KB LDS.
template <bool FP32IN>
__global__ __launch_bounds__(256) void k_gemmM(const void* __restrict__ Xv,
                                               const ushort_t* __restrict__ Bw,
                                               const float* __restrict__ b,
                                               ushort_t* __restrict__ Y) {
  __shared__ ushort_t Bs[16384];  // 32 KB
  int tid = threadIdx.x;
  for (int i = tid; i < 2048; i += 256)
    *(short8*)&Bs[i * 8] = *(const short8*)&Bw[i * 8];
  __syncthreads();
  int w = tid >> 6, lane = tid & 63;
  int m = lane & 15, q = lane >> 4;
  int rowbase = blockIdx.x * 64 + w * 16;
  int rm = rowbase + m; if (rm >= NND) rm = NND - 1;  // clamp: row m only affects row m outputs
  short8 a[4];
  if (FP32IN) {
    const float* X = (const float*)Xv;
    #pragma unroll
    for (int t = 0; t < 4; t++) {
      const float* p0 = &X[(long)rm * HD + t * 32 + q * 8];
      float4 x0 = *(const float4*)p0;
      float4 x1 = *(const float4*)(p0 + 4);
      short8 av;
      av[0] = (short)f2bf(x0.x); av[1] = (short)f2bf(x0.y);
      av[2] = (short)f2bf(x0.z); av[3] = (short)f2bf(x0.w);
      av[4] = (short)f2bf(x1.x); av[5] = (short)f2bf(x1.y);
      av[6] = (short)f2bf(x1.z); av[7] = (short)f2bf(x1.w);
      a[t] = av;
    }
  } else {
    const ushort_t* X = (const ushort_t*)Xv;
    #pragma unroll
    for (int t = 0; t < 4; t++)
      a[t] = *(const short8*)&X[(long)rm * HD + t * 32 + q * 8];
  }
  #pragma unroll
  for (int nt = 0; nt < 8; nt++) {
    f32x4 acc = {0.f, 0.f, 0.f, 0.f};
    #pragma unroll
    for (int t = 0; t < 4; t++) {
      short8 bf = *(const short8*)&Bs[((nt * 4 + t) * 64 + lane) * 8];
      acc = __builtin_amdgcn_mfma_f32_16x16x32_bf16(a[t], bf, acc, 0, 0, 0);
    }
    float bias = b[nt * 16 + m];
    #pragma unroll
    for (int reg = 0; reg < 4; reg++) {
      int r = rowbase + q * 4 + reg;
      if (r < NND) Y[(long)r * HD + nt * 16 + m] = f2bf(acc[reg] + bias);
    }
  }
}

// ---------------- aggregation: bf16 rows, fp32 accumulate, bf16 out ----------------
__global__ __launch_bounds__(256) void k_aggr(const ushort_t* __restrict__ H,
                                              const int* __restrict__ offs,
                                              const int* __restrict__ srcs,
                                              const float* __restrict__ dinv,
                                              ushort_t* __restrict__ O) {
  int g = threadIdx.x >> 5, lane = threadIdx.x & 31;
  int node = blockIdx.x * 8 + g;
  if (node >= NND) return;
  float di = dinv[node];
  float4 hv = bf4_to_f4(*(const ushort4*)&H[node * HD + lane * 4]);
  float sw = di * di;
  float4 acc;
  acc.x = hv.x * sw; acc.y = hv.y * sw; acc.z = hv.z * sw; acc.w = hv.w * sw;
  int s0 = offs[node], s1 = offs[node + 1];
  for (int base = s0; base < s1; base += 32) {
    int m = s1 - base; if (m > 32) m = 32;
    int sl = 0; float wl = 0.f;
    if (lane < m) { sl = srcs[base + lane]; wl = dinv[sl]; }
    for (int t = 0; t < m; t++) {
      int s = __shfl(sl, t, 32);
      float w = __shfl(wl, t, 32) * di;
      float4 hs = bf4_to_f4(*(const ushort4*)&H[s * HD + lane * 4]);
      acc.x += w * hs.x; acc.y += w * hs.y; acc.z += w * hs.z; acc.w += w * hs.w;
    }
  }
  ushort4 r;
  r.x = f2bf(acc.x); r.y = f2bf(acc.y); r.z = f2bf(acc.z); r.w = f2bf(acc.w);
  *(ushort4*)&O[node * HD + lane * 4] = r;
}

// ---------------- edge classifier via MFMA: 16 edges x 16 classes per wave ----------------
__global__ __launch_bounds__(256) void k_edge(const ushort_t* __restrict__ H,
                                              const int* __restrict__ row,
                                              const int* __restrict__ col,
                                              const ushort_t* __restrict__ Bp,
                                              const float* __restrict__ bfc,
                                              float* __restrict__ logits) {
  int tid = threadIdx.x;
  int w = tid >> 6, lane = tid & 63;
  int ebase = blockIdx.x * 64 + w * 16;  // 9375*64 = 600000 exactly
  int m = lane & 15, g = lane >> 4;

  short8 bf[8];
  #pragma unroll
  for (int t = 0; t < 8; t++) bf[t] = *(const short8*)&Bp[(t * 64 + lane) * 8];

  int r = row[ebase + m];
  int c = col[ebase + m];
  long br = (long)r * HD, bc = (long)c * HD;
  int ko = g * 8;

  short8 a[8];
  #pragma unroll
  for (int t = 0; t < 4; t++) {
    a[t]     = *(const short8*)&H[br + t * 32 + ko];
    a[4 + t] = *(const short8*)&H[bc + t * 32 + ko];
  }

  f32x4 acc = {0.f, 0.f, 0.f, 0.f};
  #pragma unroll
  for (int t = 0; t < 8; t++)
    acc = __builtin_amdgcn_mfma_f32_16x16x32_bf16(a[t], bf[t], acc, 0, 0, 0);

  int n = lane & 15;
  if (n < NC) {
    float bias = bfc[n];
    #pragma unroll
    for (int reg = 0; reg < 4; reg++) {
      int e = ebase + g * 4 + reg;
      logits[(long)e * NC + n] = acc[reg] + bias;
    }
  }
}

// ---------------- loss: streaming log_softmax + NLL over logits ----------------
__global__ __launch_bounds__(256) void k_loss2(const float* __restrict__ logits,
                                               const int* __restrict__ label,
                                               float* __restrict__ lossb) {
  __shared__ float Ls[4];
  int tid = threadIdx.x;
  int e = blockIdx.x * 256 + tid;
  float lp = 0.f;
  if (e < NE) {
    const float* q = logits + (long)e * NC;
    float p[NC];
    #pragma unroll
    for (int i = 0; i < 5; i++) {
      float2 v = *(const float2*)&q[i * 2];
      p[i * 2] = v.x; p[i * 2 + 1] = v.y;
    }
    float mx = p[0];
    #pragma unroll
    for (int cc = 1; cc < NC; cc++) mx = fmaxf(mx, p[cc]);
    float se = 0.f;
    #pragma unroll
    for (int cc = 0; cc < NC; cc++) se += __expf(p[cc] - mx);
    int lb = label[e];
    float plb = p[0];
    #pragma unroll
    for (int cc = 1; cc < NC; cc++) plb = (cc == lb) ? p[cc] : plb;
    lp = plb - mx - __logf(se);
  }
  #pragma unroll
  for (int off = 32; off > 0; off >>= 1) lp += __shfl_xor(lp, off, 64);
  if ((tid & 63) == 0) Ls[tid >> 6] = lp;
  __syncthreads();
  if (tid == 0) {
    float s = Ls[0] + Ls[1] + Ls[2] + Ls[3];
    unsafeAtomicAdd(lossb, s);
  }
}

__global__ void k_loss(const float* lossb, float* out) {
  out[0] = -lossb[0] / (float)NE;
}

extern "C" void kernel_launch(void* const* d_in, const int* in_sizes, int n_in,
                              void* d_out, int out_size, void* d_ws, size_t ws_size,
                              hipStream_t stream) {
  const float* features = (const float*)d_in[0];
  const float* W1  = (const float*)d_in[1];
  const float* b1  = (const float*)d_in[2];
  const float* W2  = (const float*)d_in[3];
  const float* b2  = (const float*)d_in[4];
  const float* Wfc = (const float*)d_in[5];
  const float* bfc = (const float*)d_in[6];
  const int* row   = (const int*)d_in[7];
  const int* col   = (const int*)d_in[8];
  const int* label = (const int*)d_in[9];
  float* out = (float*)d_out;

  float* ws = (float*)d_ws;
  size_t o = 0;
  float* degf = ws + o;         o += 50048;
  int*   cnt  = (int*)(ws + o); o += 50048;
  int*   offs = (int*)(ws + o); o += 50064;  // N+1
  int*   pos  = (int*)(ws + o); o += 50048;
  int*   srcs = (int*)(ws + o); o += 600064;
  float* lossb = ws + o;        o += 16;
  ushort_t* Bp  = (ushort_t*)(ws + o); o += 2048;   // Wfc fragments
  ushort_t* Bw1 = (ushort_t*)(ws + o); o += 8192;   // W1 fragments (16384 bf16)
  ushort_t* Bw2 = (ushort_t*)(ws + o); o += 8192;
  ushort_t* bufA = (ushort_t*)(ws + o); o += 3200000;
  ushort_t* bufB = (ushort_t*)(ws + o); o += 3200000;

  k_init<<<196, 256, 0, stream>>>(degf, cnt, lossb);
  k_count<<<256, 256, 0, stream>>>(row, col, degf, cnt);
  k_scan<<<1, 1024, 0, stream>>>(cnt, offs, pos, degf);
  k_fill<<<256, 256, 0, stream>>>(row, col, pos, srcs);
  k_prep_all<<<17, 256, 0, stream>>>(Wfc, W1, W2, Bp, Bw1, Bw2);

  // conv1 (fp32 features -> bf16), conv2 (bf16 -> bf16)
  k_gemmM<true><<<782, 256, 0, stream>>>((const void*)features, Bw1, b1, bufA);
  k_aggr<<<6250, 256, 0, stream>>>(bufA, offs, srcs, degf, bufB);
  k_gemmM<false><<<782, 256, 0, stream>>>((const void*)bufB, Bw2, b2, bufA);
  k_aggr<<<6250, 256, 0, stream>>>(bufA, offs, srcs, degf, bufB);
  // edge classifier (MFMA) + loss
  k_edge<<<9375, 256, 0, stream>>>(bufB, row, col, Bp, bfc, out + 1);
  k_loss2<<<2344, 256, 0, stream>>>(out + 1, label, lossb);
  k_loss<<<1, 1, 0, stream>>>(lossb, out);
}